// Round 2
// baseline (706.119 us; speedup 1.0000x reference)
//
#include <hip/hip_runtime.h>
#include <math.h>

#define BN_EPS 1e-3f
#define COL_BLOCKS 8      // N / (256 threads * 4 cols)
#define ROW_CHUNKS 128    // 2N / 128 = 128 rows per chunk
#define ROWS_PER_CHUNK 128

// Kernel A: one 64-lane wave per node. Lanes gather K=64 neighbor values
// (adj row is a coalesced 256B read; x is 32KB -> L1/L2 resident),
// shuffle-reduce, lane 0 applies BatchNorm to both halves of
// h = concat([x, x + ngh_sum]) and writes h_bn[2N].
__global__ void agg_bn_kernel(const float* __restrict__ x,
                              const int* __restrict__ adj,
                              const float* __restrict__ bn_gamma,
                              const float* __restrict__ bn_beta,
                              const float* __restrict__ bn_mean,
                              const float* __restrict__ bn_var,
                              float* __restrict__ h_bn,
                              int N, int K)
{
    int gid  = blockIdx.x * blockDim.x + threadIdx.x;
    int node = gid >> 6;
    int lane = gid & 63;
    if (node >= N) return;

    float s = 0.0f;
    for (int k = lane; k < K; k += 64) {
        int nb = adj[(size_t)node * K + k];
        s += x[nb];
    }
#pragma unroll
    for (int off = 32; off > 0; off >>= 1)
        s += __shfl_down(s, off, 64);

    if (lane == 0) {
        float xi  = x[node];
        float agg = xi + s;
        {
            float sc = rsqrtf(bn_var[node] + BN_EPS) * bn_gamma[node];
            h_bn[node] = (xi - bn_mean[node]) * sc + bn_beta[node];
        }
        {
            int j = N + node;
            float sc = rsqrtf(bn_var[j] + BN_EPS) * bn_gamma[j];
            h_bn[j] = (agg - bn_mean[j]) * sc + bn_beta[j];
        }
    }
}

// Kernel B: split-K GEMV partials, NO atomics.
// Grid: (COL_BLOCKS=8, ROW_CHUNKS=128) = 1024 blocks (4/CU), 256 threads.
// Thread owns 4 consecutive cols (float4 loads, 16B/lane, 1KiB/wave coalesced),
// accumulates ROWS_PER_CHUNK=128 rows, stores one float4 partial.
// partial[chunk*N + col] : 128 * 8192 floats = 4 MiB in ws.
__global__ void gemv_partial_kernel(const float* __restrict__ h,
                                    const float* __restrict__ W,
                                    float* __restrict__ partial,
                                    int N)
{
    __shared__ float hs[ROWS_PER_CHUNK];
    int row0 = blockIdx.y * ROWS_PER_CHUNK;
    for (int i = threadIdx.x; i < ROWS_PER_CHUNK; i += blockDim.x)
        hs[i] = h[row0 + i];
    __syncthreads();

    int col = blockIdx.x * 1024 + threadIdx.x * 4;
    const float* Wp = W + (size_t)row0 * N + col;

    float ax = 0.0f, ay = 0.0f, az = 0.0f, aw = 0.0f;
#pragma unroll 8
    for (int r = 0; r < ROWS_PER_CHUNK; ++r) {
        float4 w = *(const float4*)(Wp + (size_t)r * N);
        float hv = hs[r];
        ax = fmaf(hv, w.x, ax);
        ay = fmaf(hv, w.y, ay);
        az = fmaf(hv, w.z, az);
        aw = fmaf(hv, w.w, aw);
    }
    float4 res = make_float4(ax, ay, az, aw);
    *(float4*)(partial + (size_t)blockIdx.y * N + col) = res;
}

// Kernel C: out[j] = gelu(b[j] + sum_c partial[c][j]), exact erf form.
// Reads 4 MiB coalesced (consecutive threads -> consecutive cols per chunk).
__global__ void reduce_bias_gelu_kernel(const float* __restrict__ partial,
                                        const float* __restrict__ b,
                                        float* __restrict__ out, int N)
{
    int j = blockIdx.x * blockDim.x + threadIdx.x;
    if (j >= N) return;
    float v = b[j];
#pragma unroll 8
    for (int c = 0; c < ROW_CHUNKS; ++c)
        v += partial[(size_t)c * N + j];
    out[j] = 0.5f * v * (1.0f + erff(v * 0.70710678118654752f));
}

extern "C" void kernel_launch(void* const* d_in, const int* in_sizes, int n_in,
                              void* d_out, int out_size, void* d_ws, size_t ws_size,
                              hipStream_t stream)
{
    const float* x   = (const float*)d_in[0];   // [1, N]
    const int*   adj = (const int*)d_in[1];     // [N, K]
    // d_in[2] = edge_weights: unused by the reference
    const float* W   = (const float*)d_in[3];   // [2N, N]
    const float* b   = (const float*)d_in[4];   // [N]
    const float* g   = (const float*)d_in[5];   // bn_gamma [2N]
    const float* be  = (const float*)d_in[6];   // bn_beta  [2N]
    const float* mn  = (const float*)d_in[7];   // bn_mean  [2N]
    const float* vr  = (const float*)d_in[8];   // bn_var   [2N]
    float* out = (float*)d_out;

    int N = in_sizes[0];       // 8192
    int K = in_sizes[1] / N;   // 64

    // Workspace layout: h_bn [2N] floats | partial [ROW_CHUNKS*N] floats (4.06 MiB)
    float* h_bn    = (float*)d_ws;
    float* partial = h_bn + 2 * N;

    {
        // one 64-lane wave per node
        long long total_threads = (long long)N * 64;
        int threads = 256;
        int blocks = (int)((total_threads + threads - 1) / threads);
        agg_bn_kernel<<<blocks, threads, 0, stream>>>(x, adj, g, be, mn, vr, h_bn, N, K);
    }
    {
        dim3 grid(COL_BLOCKS, ROW_CHUNKS);
        gemv_partial_kernel<<<grid, 256, 0, stream>>>(h_bn, W, partial, N);
    }
    reduce_bias_gelu_kernel<<<(N + 255) / 256, 256, 0, stream>>>(partial, b, out, N);
}